// Round 12
// baseline (177.043 us; speedup 1.0000x reference)
//
#include <hip/hip_runtime.h>
#include <math.h>

// Problem constants (from setup_inputs): N=8, H=768, W=360, D=512
#define N_IMG 8
#define H 768
#define W 360
#define D 512
#define SY 383.5f         // (H-1)/2
#define SC 0.00436332312998582394f  // pi/(2W) = pi/720
#define NC 24             // 768/32 m-chunks
#define IPAD 384          // i dimension padded 360 -> 384
#define KSTEPS 10         // 10 x 32 = K 320 band

typedef __fp16 h2 __attribute__((ext_vector_type(2)));
struct H2X2 { h2 a, b; };        // 8B LDS entry: {img01@y, img23@y}
typedef short short8 __attribute__((ext_vector_type(8)));   // 8 bf16 (4 VGPRs)
typedef float f32x4 __attribute__((ext_vector_type(4)));

// fp32 -> bf16 pair, round-to-nearest-even, packed into one uint
__device__ inline unsigned bf16pair(float a, float b) {
    unsigned ua = __builtin_bit_cast(unsigned, a);
    unsigned ub = __builtin_bit_cast(unsigned, b);
    ua += 0x7FFFu + ((ua >> 16) & 1u);
    ub += 0x7FFFu + ((ub >> 16) & 1u);
    return (ua >> 16) | (ub & 0xFFFF0000u);
}

// ---------------------------------------------------------------------------
// Kernel 1 (fused g + Bg): each block t (= kstep) computes the g-values its
// 4 Bg rows need, directly from hG, then packs the B-frag table.
//   g[d] = (1/H) sum_k hG[k] cos(2*pi*k*d/H)
//   Bg[(t*4+j)*64+L] entry s: g[(nn + 128 - (kb+s)) mod H],
//     nn = 16j + (L&15), kb = 32t + (L>>4)*8.
// Local d-window: d in [dlo, dlo+96), dlo = 97-32t; local index
// l = 16j + (L&15) + 31 - (L>>4)*8 - s  (t cancels; l in [0,95)).
// g-sums: 96 values x 2 threads x 384 terms; hG LDS-staged (broadcast reads);
// cos via v_cos_f32 (input in revolutions; error ~1e-6 << bf16 quantization).
// Grid 10 x 256.
// ---------------------------------------------------------------------------
__global__ __launch_bounds__(256)
void build_bg_kernel(const float* __restrict__ hG, uint4* __restrict__ Bg) {
    __shared__ float hGs[H];     // 3 KB
    __shared__ float gl[96];

    const int t = blockIdx.x;    // kstep 0..9
    const int tid = threadIdx.x;

#pragma unroll
    for (int q = 0; q < 3; ++q) hGs[tid + 256 * q] = hG[tid + 256 * q];
    __syncthreads();

    if (tid < 192) {
        int l = tid >> 1, h = tid & 1;
        int d = 97 - 32 * t + l;
        int dm = d + ((d < 0) ? H : 0);
        float s = 0.f;
#pragma unroll 4
        for (int q = 0; q < 384; ++q) {
            int k = h * 384 + q;
            int prod = (k * dm) % H;
            s += hGs[k] * __builtin_amdgcn_cosf((float)prod * (1.0f / 768.0f));
        }
        s += __shfl_xor(s, 1);
        if (h == 0) gl[l] = s * (1.0f / (float)H);
    }
    __syncthreads();

    {
        int j = tid >> 6, L = tid & 63;
        int base = 16 * j + (L & 15) + 31 - (L >> 4) * 8;
        float bf[8];
#pragma unroll
        for (int s = 0; s < 8; ++s) bf[s] = gl[base - s];
        Bg[(t * 4 + j) * 64 + L] = (uint4){bf16pair(bf[0], bf[1]), bf16pair(bf[2], bf[3]),
                                           bf16pair(bf[4], bf[5]), bf16pair(bf[6], bf[7])};
    }
}

// ---------------------------------------------------------------------------
// Kernel 2: A-matrix transpose + bf16 pack (+ fused output zeroing).
// px == i exactly -> rc[n][i][m] = radon[n][m][i]: pure transpose.
// Coalesced float4 row loads -> LDS (pad 65) -> transposed bf16x8 pack ->
// contiguous uint4 store. Blocks with flat id < 1024 zero the atomic output.
// Grid (6, 24, 8) = 1152 blocks x 256 thr.
// ---------------------------------------------------------------------------
__global__ __launch_bounds__(256)
void build_rc_kernel(const float* __restrict__ radon, uint4* __restrict__ rcC,
                     float4* __restrict__ out4) {
    __shared__ float xs[32][65];   // 8.3 KB

    const int i0 = blockIdx.x * 64;
    const int c  = blockIdx.y;
    const int n  = blockIdx.z;
    const int tid = threadIdx.x;

    // fused zero of the atomic output (1024 blocks x 512 float4 = full 8 MB)
    {
        int flat = ((n * NC) + c) * 6 + blockIdx.x;
        if (flat < 1024) {
            out4[flat * 512 + tid]       = make_float4(0.f, 0.f, 0.f, 0.f);
            out4[flat * 512 + 256 + tid] = make_float4(0.f, 0.f, 0.f, 0.f);
        }
    }

    // load radon[m = 32c + mr][i0 + lane8*8 .. +8) coalesced
    {
        int mr    = tid >> 3;      // 0..31
        int lane8 = tid & 7;
        int ib = i0 + lane8 * 8;
        const float* src = radon + ((size_t)n * H + 32 * c + mr) * W + ib;
        float4 v0, v1;
        if (ib + 7 < W) {          // 360 % 8 == 0: tiles all-valid or all-invalid
            v0 = *(const float4*)src;
            v1 = *(const float4*)(src + 4);
        } else {
            v0 = make_float4(0.f, 0.f, 0.f, 0.f);
            v1 = make_float4(0.f, 0.f, 0.f, 0.f);
        }
        *(float4*)&xs[mr][lane8 * 8]     = v0;
        *(float4*)&xs[mr][lane8 * 8 + 4] = v1;
    }
    __syncthreads();

    // transposed pack: 8 m-values (oct) for angle i0+il
    const int il  = tid >> 2;      // 0..63
    const int oct = tid & 3;
    float v[8];
#pragma unroll
    for (int s = 0; s < 8; ++s) v[s] = xs[oct * 8 + s][il];
    uint4 pk = {bf16pair(v[0], v[1]), bf16pair(v[2], v[3]),
                bf16pair(v[4], v[5]), bf16pair(v[6], v[7])};
    rcC[(((size_t)n * NC + c) * IPAD + i0 + il) * 4 + oct] = pk;
}

// ---------------------------------------------------------------------------
// Kernel 3: banded circulant filtering, barrier-free MFMA GEMM.
// Tile 16 i x 32 y (wave w = image grp*4+w); 1 A-frag + 2 B-frags + 2 MFMA
// per kstep, 10 ksteps. Grid (24 y, 23 i, 2 grp) = 1104 blocks = 4.3/CU for
// L2-load latency hiding (round-11's 552 was TLP-starved). Epilogue: fp16
// exchange through 4 KB LDS, coalesced uint2 stores of {img0..3} pairs.
// ---------------------------------------------------------------------------
__global__ __launch_bounds__(256)
void filt_gemm_kernel(const uint4* __restrict__ rcC, const uint4* __restrict__ Bg,
                      unsigned short* __restrict__ colp) {
    __shared__ _Float16 lx[16][32][4];   // 4 KB

    const int grp = blockIdx.z;
    const int i0 = blockIdx.y * 16;   // angle-tile base
    const int y0 = blockIdx.x * 32;   // y-tile base
    const int wv = threadIdx.x >> 6;  // wave 0..3 = image grp*4+wv
    const int L  = threadIdx.x & 63;  // lane

    const int c0 = (y0 / 32 + 20) % NC;   // first band chunk: (y0-128)/32 mod 24
    const uint4* An = rcC + (size_t)(grp * 4 + wv) * NC * IPAD * 4;
    const int arow = i0 + (L & 15);
    const int aoff = L >> 4;

    f32x4 acc[2];
    acc[0] = (f32x4){0.f, 0.f, 0.f, 0.f};
    acc[1] = (f32x4){0.f, 0.f, 0.f, 0.f};

    for (int t = 0; t < KSTEPS; ++t) {
        int c = c0 + t;
        c -= (c >= NC) ? NC : 0;
        short8 a = __builtin_bit_cast(short8, An[((size_t)c * IPAD + arow) * 4 + aoff]);
#pragma unroll
        for (int j = 0; j < 2; ++j) {
            short8 b = __builtin_bit_cast(short8, Bg[(t * 4 + j) * 64 + L]);
            acc[j] = __builtin_amdgcn_mfma_f32_16x16x32_bf16(a, b, acc[j], 0, 0, 0);
        }
    }

    // exchange: D row=(L>>4)*4+r -> local i, col=L&15 -> local y (frag j)
#pragma unroll
    for (int j = 0; j < 2; ++j) {
#pragma unroll
        for (int r = 0; r < 4; ++r) {
            int ilc = (L >> 4) * 4 + r;
            int ylc = j * 16 + (L & 15);
            lx[ilc][ylc][wv] = (_Float16)(acc[j][r] * SC);
        }
    }
    __syncthreads();

    // coalesced packed store: entry (i, y) = 4 images' halves (8 B)
    unsigned short* cp = colp + (size_t)grp * W * H * 4;
#pragma unroll
    for (int k2 = 0; k2 < 2; ++k2) {
        int e = threadIdx.x + k2 * 256;   // 0..511
        int ilc = e >> 5, ylc = e & 31;
        int ig = i0 + ilc;
        if (ig < W) {
            uint2 v = *(const uint2*)&lx[ilc][ylc][0];
            *(uint2*)&cp[((size_t)ig * H + y0 + ylc) * 4] = v;
        }
    }
}

// ---------------------------------------------------------------------------
// Kernel 4: backprojection, 4 images/block (round-10 structure: LDS-pipe
// bound at ~80 us floor, conflicts 0, FETCH 2.2 MB). Per-angle constants now
// computed in the prologue (90 cosf/sinf once per block; LDS-broadcast reads)
// -- kills the ang buffer + one upstream launch dependency.
// Grid 1024 x 512 thr = 4 blocks/CU; XCD swizzle bz = bid & 7.
// ---------------------------------------------------------------------------
__global__ __launch_bounds__(512, 8)
void backproj_kernel(const unsigned short* __restrict__ colp, float* __restrict__ outb) {
    __shared__ __align__(16) H2X2 colh[2][H];   // 12 KB
    __shared__ float2 angs[W / 4];              // 720 B

    const int bid = blockIdx.x;
    const int bz  = bid & 7;             // XCD-local under round-robin dispatch
    const int tle = bid >> 3;            // 0..127: 16 u-tiles x 8 v-tiles
    const int g  = bz >> 2;              // image-group
    const int aq = bz & 3;               // angle quarter
    const int a0 = aq * (W / 4);         // 90 angles per block
    const int u0 = (tle >> 3) * 32;
    const int v0 = (tle & 7) * 64;
    const int tid = threadIdx.x;
    const int lane = tid & 63;
    const int tu = tid >> 6;             // 0..7

    const float vf = (float)(v0 + lane - D / 2);
    float uf[4];
#pragma unroll
    for (int r = 0; r < 4; ++r) uf[r] = (float)(u0 + tu + 8 * r - D / 2);

    const h2 hz = {(__fp16)0.f, (__fp16)0.f};
    float acc[4][4];                     // fp32 accumulators [r][nn]
    h2 haccA[4], haccB[4];               // fp16 packed partials
#pragma unroll
    for (int r = 0; r < 4; ++r) {
#pragma unroll
        for (int nn = 0; nn < 4; ++nn) acc[r][nn] = 0.f;
        haccA[r] = hz;
        haccB[r] = hz;
    }

    const uint2* cp = (const uint2*)colp + (size_t)g * W * H;

    const int y1 = tid;                  // 0..511
    const int y2 = tid + 512;            // 512..767 (tid < 256 only)

    // prologue: per-angle constants + stage angle a0 into buffer 0
    if (tid < W / 4) {
        float th = (float)(a0 + tid) * 0.00872664625997164788f;  // pi/360
        float r = SY / 384.0f;
        angs[tid] = make_float2(cosf(th) * r, -sinf(th) * r);
    }
    {
        const int ab = a0 * H;
        colh[0][y1] = __builtin_bit_cast(H2X2, cp[ab + y1]);
        if (tid < 256) colh[0][y2] = __builtin_bit_cast(H2X2, cp[ab + y2]);
    }
    __syncthreads();

    for (int j = 0; j < W / 4; ++j) {
        int a = a0 + j;
        // prefetch next angle's packed column into registers
        int an = (j + 1 < W / 4) ? (a + 1) : a;
        const int ab = an * H;
        uint2 d = cp[ab + y1];
        uint2 e = make_uint2(0u, 0u);
        if (tid < 256) e = cp[ab + y2];

        const int cb2 = j & 1;
        float2 AB = angs[j];             // LDS broadcast (same addr all lanes)
        float base = fmaf(vf, AB.x, SY);
#pragma unroll
        for (int r = 0; r < 4; ++r) {
            float py = fmaf(uf[r], AB.y, base);
            float wy = __builtin_amdgcn_fractf(py);
            int iy = (int)py;                          // trunc == floor (py > 0)
            uint2 lo_raw = *(const uint2*)&colh[cb2][iy];       // ds_read_b64
            uint2 hi_raw = *(const uint2*)&colh[cb2][iy + 1];   // ds_read_b64
            H2X2 lo = __builtin_bit_cast(H2X2, lo_raw);
            H2X2 hi = __builtin_bit_cast(H2X2, hi_raw);
            h2 wy2 = __builtin_amdgcn_cvt_pkrtz(wy, wy);
            haccA[r] += lo.a + wy2 * (hi.a - lo.a);    // v_pk_sub/fma/add_f16
            haccB[r] += lo.b + wy2 * (hi.b - lo.b);
        }

        // flush fp16 partials to fp32 every 16 angles
        if ((j & 15) == 15) {
#pragma unroll
            for (int r = 0; r < 4; ++r) {
                acc[r][0] += (float)haccA[r].x;
                acc[r][1] += (float)haccA[r].y;
                acc[r][2] += (float)haccB[r].x;
                acc[r][3] += (float)haccB[r].y;
                haccA[r] = hz;
                haccB[r] = hz;
            }
        }

        // write prefetched angle into the other buffer (disjoint from read buf)
        colh[cb2 ^ 1][y1] = __builtin_bit_cast(H2X2, d);
        if (tid < 256) colh[cb2 ^ 1][y2] = __builtin_bit_cast(H2X2, e);
        __syncthreads();
    }

    // final flush + atomic accumulate into output (4 adds/element total)
#pragma unroll
    for (int r = 0; r < 4; ++r) {
        acc[r][0] += (float)haccA[r].x;
        acc[r][1] += (float)haccA[r].y;
        acc[r][2] += (float)haccB[r].x;
        acc[r][3] += (float)haccB[r].y;
        int u = u0 + tu + 8 * r;
#pragma unroll
        for (int nn = 0; nn < 4; ++nn) {
            size_t idx = ((size_t)(g * 4 + nn) * D + u) * D + v0 + lane;
            atomicAdd(&outb[idx], acc[r][nn]);
        }
    }
}

// ---------------------------------------------------------------------------
// Workspace layout:
//   [8192, 49152)          Bg (2560 uint4 = 40 KB B-frag table)
//   [65536, 4489216)       colp (2 grp x 360 x 768 x 8B fp16-packed columns)
//   [4489216, 9207808)     rcC (8 x 24 x 384 x 64B bf16 A-frag chunks)
// ---------------------------------------------------------------------------
extern "C" void kernel_launch(void* const* d_in, const int* in_sizes, int n_in,
                              void* d_out, int out_size, void* d_ws, size_t ws_size,
                              hipStream_t stream) {
    const float* radon = (const float*)d_in[0];
    const float* hG    = (const float*)d_in[1];
    float* out = (float*)d_out;

    uint4*  Bg   = (uint4*)((char*)d_ws + 8192);
    unsigned short* colp = (unsigned short*)((char*)d_ws + 65536);
    uint4*  rcC  = (uint4*)((char*)d_ws + 4489216);

    build_bg_kernel<<<10, 256, 0, stream>>>(hG, Bg);
    build_rc_kernel<<<dim3(6, NC, N_IMG), 256, 0, stream>>>(radon, rcC, (float4*)out);
    filt_gemm_kernel<<<dim3(24, 23, 2), 256, 0, stream>>>(rcC, Bg, colp);
    backproj_kernel<<<1024, 512, 0, stream>>>(colp, out);
}